// Round 8
// baseline (106.415 us; speedup 1.0000x reference)
//
#include <hip/hip_runtime.h>

typedef __bf16 bf16x8 __attribute__((ext_vector_type(8)));
typedef float f32x4 __attribute__((ext_vector_type(4)));

__device__ __forceinline__ unsigned short f2b(float f) {
  union { float f; unsigned int u; } v;
  v.f = f;
  unsigned int r = v.u + 0x7fffu + ((v.u >> 16) & 1u);
  return (unsigned short)(r >> 16);
}
__device__ __forceinline__ float b2f_lo(unsigned int u) {
  union { unsigned int u; float f; } v;
  v.u = u << 16;
  return v.f;
}
__device__ __forceinline__ float b2f_hi(unsigned int u) {
  union { unsigned int u; float f; } v;
  v.u = u & 0xffff0000u;
  return v.f;
}

// ---------------- kernel 0: weight f32 [O][C][9] -> bf16 k-major [O][k*256+c] --
__global__ __launch_bounds__(256) void cast_weight(
    const float* __restrict__ w, unsigned short* __restrict__ wb) {
  int idx = blockIdx.x * 256 + threadIdx.x;  // 589824
  int o = idx / 2304;
  int r = idx - o * 2304;
  int k = r >> 8;
  int c = r & 255;
  wb[idx] = f2b(w[(size_t)(o * 256 + c) * 9 + k]);
}

// ---------------- kernel 1: x NCHW f32 -> NHWC bf16  x_t[b][h][w][c] ----------
__global__ __launch_bounds__(256) void transpose_x(
    const float* __restrict__ x, unsigned short* __restrict__ xt) {
  const int bid = blockIdx.x;
  const int b = bid >> 8;
  const int h = (bid >> 2) & 63;
  const int cq = bid & 3;
  const int t = threadIdx.x;
  const int wave = t >> 6, lane = t & 63;
  __shared__ float lds[64][65];
  const int wpos = t >> 2, sub = t & 3;
  const int cl0 = wave * 4 + (lane >> 4);
  const int w0 = (lane & 15) * 4;
#pragma unroll
  for (int iter = 0; iter < 4; ++iter) {
    const int cl = iter * 16 + cl0;
    const int c = cq * 64 + cl;
    float4 v = *(const float4*)(x + (((size_t)b * 256 + c) * 64 + h) * 64 + w0);
    lds[cl][w0] = v.x; lds[cl][w0 + 1] = v.y;
    lds[cl][w0 + 2] = v.z; lds[cl][w0 + 3] = v.w;
  }
  __syncthreads();
  unsigned short hb[16];
#pragma unroll
  for (int j = 0; j < 16; ++j) hb[j] = f2b(lds[sub * 16 + j][wpos]);
  uint4 p0, p1;
  p0.x = (unsigned)hb[0] | ((unsigned)hb[1] << 16);
  p0.y = (unsigned)hb[2] | ((unsigned)hb[3] << 16);
  p0.z = (unsigned)hb[4] | ((unsigned)hb[5] << 16);
  p0.w = (unsigned)hb[6] | ((unsigned)hb[7] << 16);
  p1.x = (unsigned)hb[8] | ((unsigned)hb[9] << 16);
  p1.y = (unsigned)hb[10] | ((unsigned)hb[11] << 16);
  p1.z = (unsigned)hb[12] | ((unsigned)hb[13] << 16);
  p1.w = (unsigned)hb[14] | ((unsigned)hb[15] << 16);
  unsigned short* dst = xt + (((size_t)b * 64 + h) * 64 + wpos) * 256 + cq * 64 + sub * 16;
  *(uint4*)dst = p0;
  *(uint4*)(dst + 8) = p1;
}

// ---------------- fused: sample + GEMM, BK=64, 3-buf A, 2-deep G2L pipeline ---
// block = (b, nt=h). Out tile [256 o][64 hw]. 36 phases. 512 thr = 8 waves,
// m-split 32 rows/wave, fm=2 x fn=4. CUT&1: skip MFMA+frag reads (ablation).
#define G2L(gsrc, ldst)                                                            \
  __builtin_amdgcn_global_load_lds(                                                \
      (const __attribute__((address_space(1))) void*)(gsrc),                       \
      (__attribute__((address_space(3))) void*)(ldst), 16, 0, 0)

__device__ __forceinline__ void combine8(uint4 q0, uint4 q1, uint4 q2, uint4 q3,
                                         float4 wt, __bf16* dst) {
  float v0 = wt.x * b2f_lo(q0.x), v1 = wt.x * b2f_hi(q0.x);
  float v2 = wt.x * b2f_lo(q0.y), v3 = wt.x * b2f_hi(q0.y);
  float v4 = wt.x * b2f_lo(q0.z), v5 = wt.x * b2f_hi(q0.z);
  float v6 = wt.x * b2f_lo(q0.w), v7 = wt.x * b2f_hi(q0.w);
  v0 += wt.y * b2f_lo(q1.x); v1 += wt.y * b2f_hi(q1.x);
  v2 += wt.y * b2f_lo(q1.y); v3 += wt.y * b2f_hi(q1.y);
  v4 += wt.y * b2f_lo(q1.z); v5 += wt.y * b2f_hi(q1.z);
  v6 += wt.y * b2f_lo(q1.w); v7 += wt.y * b2f_hi(q1.w);
  v0 += wt.z * b2f_lo(q2.x); v1 += wt.z * b2f_hi(q2.x);
  v2 += wt.z * b2f_lo(q2.y); v3 += wt.z * b2f_hi(q2.y);
  v4 += wt.z * b2f_lo(q2.z); v5 += wt.z * b2f_hi(q2.z);
  v6 += wt.z * b2f_lo(q2.w); v7 += wt.z * b2f_hi(q2.w);
  v0 += wt.w * b2f_lo(q3.x); v1 += wt.w * b2f_hi(q3.x);
  v2 += wt.w * b2f_lo(q3.y); v3 += wt.w * b2f_hi(q3.y);
  v4 += wt.w * b2f_lo(q3.z); v5 += wt.w * b2f_hi(q3.z);
  v6 += wt.w * b2f_lo(q3.w); v7 += wt.w * b2f_hi(q3.w);
  uint4 r;
  r.x = (unsigned)f2b(v0) | ((unsigned)f2b(v1) << 16);
  r.y = (unsigned)f2b(v2) | ((unsigned)f2b(v3) << 16);
  r.z = (unsigned)f2b(v4) | ((unsigned)f2b(v5) << 16);
  r.w = (unsigned)f2b(v6) | ((unsigned)f2b(v7) << 16);
  *(uint4*)dst = r;
}

template <int CUT>
__global__ __launch_bounds__(512) void dcn_fused(
    const unsigned short* __restrict__ xt, const float* __restrict__ off,
    const float* __restrict__ mask, const __bf16* __restrict__ wbf,
    const float* __restrict__ bias, float* __restrict__ out) {
  extern __shared__ char smem_raw[];
  __bf16* As = (__bf16*)smem_raw;                        // 3 x 16384 el = 98304 B
  __bf16* Bs = As + 49152;                               // 2 x 4096 el  = 16384 B
  float* swt = (float*)(Bs + 8192);                      // [9][64][4] f32 = 9216 B
  unsigned short* sidx = (unsigned short*)(swt + 2304);  // [9][64][4] u16 = 4608 B

  const int bid = blockIdx.x;
  const int id = ((bid & 7) << 5) | (bid >> 3);  // bijective, XCD-contig (256=8*32)
  const int b = id >> 6;
  const int nt = id & 63;  // h row

  const int tid = threadIdx.x;
  const int lane = tid & 63;
  const int wave = tid >> 6;  // 8 waves, m-split: rows wave*32..wave*32+31
  const int lh = lane & 15, lg = lane >> 4;

  // ---- precompute per-(pos,k) tap weights & packed indices ----
  for (int e = tid; e < 576; e += 512) {
    const int k = e / 64;    // 0..8
    const int pl = e & 63;   // = w
    float oy = off[(((size_t)b * 18 + 2 * k) * 64 + nt) * 64 + pl];
    float ox = off[(((size_t)b * 18 + 2 * k + 1) * 64 + nt) * 64 + pl];
    float m = mask[(((size_t)b * 9 + k) * 64 + nt) * 64 + pl];
    float py = oy + (float)(nt - 1 + k / 3);
    float px = ox + (float)(pl - 1 + k % 3);
    float y0f = floorf(py), x0f = floorf(px);
    float ly = py - y0f, lx = px - x0f;
    float hy = 1.f - ly, hx = 1.f - lx;
    int y0 = (int)y0f, x0 = (int)x0f;
    int y1 = y0 + 1, x1 = x0 + 1;
    bool vy0 = (y0 >= 0) && (y0 < 64);
    bool vy1 = (y1 >= 0) && (y1 < 64);
    bool vx0 = (x0 >= 0) && (x0 < 64);
    bool vx1 = (x1 >= 0) && (x1 < 64);
    int yc0 = min(max(y0, 0), 63), yc1 = min(max(y1, 0), 63);
    int xc0 = min(max(x0, 0), 63), xc1 = min(max(x1, 0), 63);
    unsigned short* sp = sidx + (k * 64 + pl) * 4;
    float* wp = swt + (k * 64 + pl) * 4;
    sp[0] = (unsigned short)(yc0 * 64 + xc0);
    sp[1] = (unsigned short)(yc0 * 64 + xc1);
    sp[2] = (unsigned short)(yc1 * 64 + xc0);
    sp[3] = (unsigned short)(yc1 * 64 + xc1);
    wp[0] = (vy0 && vx0) ? hy * hx * m : 0.f;
    wp[1] = (vy0 && vx1) ? hy * lx * m : 0.f;
    wp[2] = (vy1 && vx0) ? ly * hx * m : 0.f;
    wp[3] = (vy1 && vx1) ? ly * lx * m : 0.f;
  }

  // ---- A staging: 4 G2L/thread/phase, 32-wide subtile XOR swizzle ----
  const __bf16* aSrc[4];
  int aDst[4];
#pragma unroll
  for (int j = 0; j < 4; ++j) {
    const int q = j * 512 + tid;   // 0..2047
    const int kh = q >> 10;
    const int r = q & 1023;
    const int row = r >> 2;
    const int swz = (r & 3) ^ ((row >> 1) & 3);
    aSrc[j] = wbf + (size_t)row * 2304 + kh * 32 + swz * 8;
    aDst[j] = q * 8;
  }

  // ---- B build: 8 threads/pos, 8 channels each ----
  const int pos = tid >> 3;  // 0..63
  const int ci = tid & 7;
  const unsigned short* xtb = xt + (size_t)b * 1048576 + ci * 8;
  const int bsw = (ci >> 2) * 2048 + pos * 32 + (((ci & 3) ^ ((pos >> 1) & 3)) * 8);

  // ---- MFMA fragment offsets ----
  const int csw = (lg ^ ((lh >> 1) & 3)) * 8;
  int aoff[2], boff[4];
#pragma unroll
  for (int fm = 0; fm < 2; ++fm) aoff[fm] = (wave * 32 + fm * 16 + lh) * 32 + csw;
#pragma unroll
  for (int fn = 0; fn < 4; ++fn) boff[fn] = (fn * 16 + lh) * 32 + csw;

#define MFMA_PHASE(AB, BB)                                                         \
  do {                                                                             \
    if constexpr ((CUT & 1) == 0) {                                                \
      const __bf16* Ab = As + (AB) * 16384;                                        \
      const __bf16* Bb = Bs + (BB) * 4096;                                         \
      bf16x8 a0[2], a1[2], b0[4], b1[4];                                           \
      _Pragma("unroll") for (int fm = 0; fm < 2; ++fm) {                           \
        a0[fm] = *(const bf16x8*)(Ab + aoff[fm]);                                  \
        a1[fm] = *(const bf16x8*)(Ab + 8192 + aoff[fm]);                           \
      }                                                                            \
      _Pragma("unroll") for (int fn = 0; fn < 4; ++fn) {                           \
        b0[fn] = *(const bf16x8*)(Bb + boff[fn]);                                  \
        b1[fn] = *(const bf16x8*)(Bb + 2048 + boff[fn]);                           \
      }                                                                            \
      __builtin_amdgcn_s_setprio(1);                                               \
      _Pragma("unroll") for (int fm = 0; fm < 2; ++fm)                             \
          _Pragma("unroll") for (int fn = 0; fn < 4; ++fn) {                       \
        acc[fm][fn] = __builtin_amdgcn_mfma_f32_16x16x32_bf16(                     \
            a0[fm], b0[fn], acc[fm][fn], 0, 0, 0);                                 \
        acc[fm][fn] = __builtin_amdgcn_mfma_f32_16x16x32_bf16(                     \
            a1[fm], b1[fn], acc[fm][fn], 0, 0, 0);                                 \
      }                                                                            \
      __builtin_amdgcn_s_setprio(0);                                               \
    }                                                                              \
  } while (0)

#define WAIT_BAR(N)                                                                \
  do {                                                                             \
    asm volatile("s_waitcnt vmcnt(" #N ") lgkmcnt(0)" ::: "memory");               \
    __builtin_amdgcn_sched_barrier(0);                                             \
    __builtin_amdgcn_s_barrier();                                                  \
  } while (0)

#define STAGE_A(KT, BUF)                                                           \
  do {                                                                             \
    if constexpr ((CUT & 2) == 0) {                                                \
      __bf16* AsD = As + (BUF) * 16384;                                            \
      G2L(aSrc[0] + (KT) * 64, AsD + aDst[0]);                                     \
      G2L(aSrc[1] + (KT) * 64, AsD + aDst[1]);                                     \
      G2L(aSrc[2] + (KT) * 64, AsD + aDst[2]);                                     \
      G2L(aSrc[3] + (KT) * 64, AsD + aDst[3]);                                     \
    }                                                                              \
  } while (0)

#define LOADTAPS(Q0, Q1, Q2, Q3, KIDX, CO)                                         \
  do {                                                                             \
    uint2 su = *(const uint2*)(sidx + (KIDX) * 4);                                 \
    Q0 = *(const uint4*)(xtb + ((su.x & 0xFFFFu) << 8) + (CO));                    \
    Q1 = *(const uint4*)(xtb + ((su.x >> 16) << 8) + (CO));                        \
    Q2 = *(const uint4*)(xtb + ((su.y & 0xFFFFu) << 8) + (CO));                    \
    Q3 = *(const uint4*)(xtb + ((su.y >> 16) << 8) + (CO));                        \
  } while (0)

  // phase p: stage A(p+2) -> buf AN; taps(p+2) -> QL; combine(QC = taps(p+1))
  // -> Bs[BB^1]; MFMA(tile p: As[AB], Bs[BB]).  2-deep A pipeline: combine's
  // implicit vmcnt(8) retires G2L(p+1) (issued 1.3 phases earlier); the barrier
  // itself leaves G2L(p+2)+taps(p+2) in flight (vmcnt(8) = no-op).
#define PHASE(P_, AB, AN, BB, QL0, QL1, QL2, QL3, QC0, QC1, QC2, QC3)              \
  do {                                                                             \
    const int kt1 = (P_) + 1, kt2 = (P_) + 2;                                      \
    STAGE_A(kt2, AN);                                                              \
    __builtin_amdgcn_sched_barrier(0);                                             \
    float4 wt4 = *(const float4*)(swt + ((kt1 >> 2) * 64 + pos) * 4);              \
    LOADTAPS(QL0, QL1, QL2, QL3, (kt2 >> 2) * 64 + pos, (kt2 & 3) * 64);           \
    combine8(QC0, QC1, QC2, QC3, wt4, Bs + ((BB) ^ 1) * 4096 + bsw);               \
    MFMA_PHASE(AB, BB);                                                            \
    WAIT_BAR(8);                                                                   \
  } while (0)

  f32x4 acc[2][4] = {};
  uint4 qA0, qA1, qA2, qA3, qB0, qB1, qB2, qB3;

  __syncthreads();  // swt/sidx ready

  // ---- prologue: build B(0); stage A(0),A(1); taps(1) ----
  {
    float4 wt0 = *(const float4*)(swt + pos * 4);
    LOADTAPS(qA0, qA1, qA2, qA3, pos, 0);
    combine8(qA0, qA1, qA2, qA3, wt0, Bs + bsw);
    STAGE_A(0, 0);
    STAGE_A(1, 1);
    __builtin_amdgcn_sched_barrier(0);
    LOADTAPS(qB0, qB1, qB2, qB3, pos, 64);
    WAIT_BAR(8);  // retires G2L(0); G2L(1)+taps(1) stay in flight
  }

  for (int p = 0; p < 30; p += 6) {
    PHASE(p + 0, 0, 2, 0, qA0, qA1, qA2, qA3, qB0, qB1, qB2, qB3);
    PHASE(p + 1, 1, 0, 1, qB0, qB1, qB2, qB3, qA0, qA1, qA2, qA3);
    PHASE(p + 2, 2, 1, 0, qA0, qA1, qA2, qA3, qB0, qB1, qB2, qB3);
    PHASE(p + 3, 0, 2, 1, qB0, qB1, qB2, qB3, qA0, qA1, qA2, qA3);
    PHASE(p + 4, 1, 0, 0, qA0, qA1, qA2, qA3, qB0, qB1, qB2, qB3);
    PHASE(p + 5, 2, 1, 1, qB0, qB1, qB2, qB3, qA0, qA1, qA2, qA3);
  }
  PHASE(30, 0, 2, 0, qA0, qA1, qA2, qA3, qB0, qB1, qB2, qB3);
  PHASE(31, 1, 0, 1, qB0, qB1, qB2, qB3, qA0, qA1, qA2, qA3);
  PHASE(32, 2, 1, 0, qA0, qA1, qA2, qA3, qB0, qB1, qB2, qB3);
  PHASE(33, 0, 2, 1, qB0, qB1, qB2, qB3, qA0, qA1, qA2, qA3);
  // ---- tail: phase 34 (no stage/taps), phase 35 (MFMA only) ----
  {
    float4 wt4 = *(const float4*)(swt + (8 * 64 + pos) * 4);
    combine8(qB0, qB1, qB2, qB3, wt4, Bs + 4096 + bsw);  // B(35) from taps(35)
    MFMA_PHASE(1, 0);                                    // tile 34
    WAIT_BAR(0);
    MFMA_PHASE(2, 1);                                    // tile 35
  }

  // ---- epilogue ----
  float* outb = out + (size_t)b * 1048576 + (size_t)nt * 64;
#pragma unroll
  for (int fm = 0; fm < 2; ++fm) {
#pragma unroll
    for (int i = 0; i < 4; ++i) {
      const int o = wave * 32 + fm * 16 + lg * 4 + i;
      const float bs = bias[o];
      float* orow = outb + (size_t)o * 4096 + lh;
#pragma unroll
      for (int fn = 0; fn < 4; ++fn) orow[fn * 16] = acc[fm][fn][i] + bs;
    }
  }
#undef MFMA_PHASE
#undef WAIT_BAR
#undef STAGE_A
#undef LOADTAPS
#undef PHASE
}

extern "C" void kernel_launch(void* const* d_in, const int* in_sizes, int n_in,
                              void* d_out, int out_size, void* d_ws, size_t ws_size,
                              hipStream_t stream) {
  const float* x = (const float*)d_in[0];
  const float* off = (const float*)d_in[1];
  const float* mask = (const float*)d_in[2];
  const float* wgt = (const float*)d_in[3];
  const float* bias = (const float*)d_in[4];
  float* out = (float*)d_out;

  unsigned short* wbf = (unsigned short*)d_ws;   // 256*2304 bf16 = 1.2 MB
  unsigned short* xtp = wbf + 589824ull;         // 4*64*64*256 bf16 = 8.4 MB
  float* abl = (float*)(xtp + 4194304ull);       // ablation scratch, 16.8 MB

  const int smem_bytes = 98304 + 16384 + 9216 + 4608;  // 128512 -> 1 block/CU
  (void)hipFuncSetAttribute(reinterpret_cast<const void*>(&dcn_fused<0>),
                            hipFuncAttributeMaxDynamicSharedMemorySize, smem_bytes);
  (void)hipFuncSetAttribute(reinterpret_cast<const void*>(&dcn_fused<1>),
                            hipFuncAttributeMaxDynamicSharedMemorySize, smem_bytes);

  cast_weight<<<2304, 256, 0, stream>>>(wgt, wbf);
  transpose_x<<<1024, 256, 0, stream>>>(x, xtp);
  // V0: real result (2-deep A pipeline)
  dcn_fused<0><<<256, 512, smem_bytes, stream>>>(xtp, off, mask, (const __bf16*)wbf,
                                                 bias, out);
  // V1 ablation: no MFMA / no frag reads -> isolates LDS-read + MFMA share
  dcn_fused<1><<<256, 512, smem_bytes, stream>>>(xtp, off, mask, (const __bf16*)wbf,
                                                 bias, abl);
}

// Round 9
// 74.197 us; speedup vs baseline: 1.4342x; 1.4342x over previous
//
#include <hip/hip_runtime.h>

typedef __bf16 bf16x8 __attribute__((ext_vector_type(8)));
typedef float f32x4 __attribute__((ext_vector_type(4)));

__device__ __forceinline__ unsigned short f2b(float f) {
  union { float f; unsigned int u; } v;
  v.f = f;
  unsigned int r = v.u + 0x7fffu + ((v.u >> 16) & 1u);
  return (unsigned short)(r >> 16);
}
__device__ __forceinline__ float b2f_lo(unsigned int u) {
  union { unsigned int u; float f; } v;
  v.u = u << 16;
  return v.f;
}
__device__ __forceinline__ float b2f_hi(unsigned int u) {
  union { unsigned int u; float f; } v;
  v.u = u & 0xffff0000u;
  return v.f;
}

// ---------------- kernel 0: weight f32 [O][C][9] -> bf16 k-major [O][k*256+c] --
__global__ __launch_bounds__(256) void cast_weight(
    const float* __restrict__ w, unsigned short* __restrict__ wb) {
  int idx = blockIdx.x * 256 + threadIdx.x;  // 589824
  int o = idx / 2304;
  int r = idx - o * 2304;
  int k = r >> 8;
  int c = r & 255;
  wb[idx] = f2b(w[(size_t)(o * 256 + c) * 9 + k]);
}

// ---------------- kernel 1: x NCHW f32 -> NHWC bf16  x_t[b][h][w][c] ----------
__global__ __launch_bounds__(256) void transpose_x(
    const float* __restrict__ x, unsigned short* __restrict__ xt) {
  const int bid = blockIdx.x;
  const int b = bid >> 8;
  const int h = (bid >> 2) & 63;
  const int cq = bid & 3;
  const int t = threadIdx.x;
  const int wave = t >> 6, lane = t & 63;
  __shared__ float lds[64][65];
  const int wpos = t >> 2, sub = t & 3;
  const int cl0 = wave * 4 + (lane >> 4);
  const int w0 = (lane & 15) * 4;
#pragma unroll
  for (int iter = 0; iter < 4; ++iter) {
    const int cl = iter * 16 + cl0;
    const int c = cq * 64 + cl;
    float4 v = *(const float4*)(x + (((size_t)b * 256 + c) * 64 + h) * 64 + w0);
    lds[cl][w0] = v.x; lds[cl][w0 + 1] = v.y;
    lds[cl][w0 + 2] = v.z; lds[cl][w0 + 3] = v.w;
  }
  __syncthreads();
  unsigned short hb[16];
#pragma unroll
  for (int j = 0; j < 16; ++j) hb[j] = f2b(lds[sub * 16 + j][wpos]);
  uint4 p0, p1;
  p0.x = (unsigned)hb[0] | ((unsigned)hb[1] << 16);
  p0.y = (unsigned)hb[2] | ((unsigned)hb[3] << 16);
  p0.z = (unsigned)hb[4] | ((unsigned)hb[5] << 16);
  p0.w = (unsigned)hb[6] | ((unsigned)hb[7] << 16);
  p1.x = (unsigned)hb[8] | ((unsigned)hb[9] << 16);
  p1.y = (unsigned)hb[10] | ((unsigned)hb[11] << 16);
  p1.z = (unsigned)hb[12] | ((unsigned)hb[13] << 16);
  p1.w = (unsigned)hb[14] | ((unsigned)hb[15] << 16);
  unsigned short* dst = xt + (((size_t)b * 64 + h) * 64 + wpos) * 256 + cq * 64 + sub * 16;
  *(uint4*)dst = p0;
  *(uint4*)(dst + 8) = p1;
}

// ---------------- fused: ring-4 pipeline, barrier per 2 tiles ----------------
// block = (b, nt=h, nh). Out tile [256 o][32 hw]. 72 tiles of K=32, 36 barriers.
// 256 thr = 4 waves (m-split 64 rows, fm=4 x fn=2). LDS 79.7KB -> 2 blocks/CU.
// Every load gets >= 1 full superphase of slack before its certifying wait.
#define G2L(gsrc, ldst)                                                            \
  __builtin_amdgcn_global_load_lds(                                                \
      (const __attribute__((address_space(1))) void*)(gsrc),                       \
      (__attribute__((address_space(3))) void*)(ldst), 16, 0, 0)

__device__ __forceinline__ void combine4(uint2 q0, uint2 q1, uint2 q2, uint2 q3,
                                         float4 wt, __bf16* dst) {
  float v0 = wt.x * b2f_lo(q0.x) + wt.y * b2f_lo(q1.x) +
             wt.z * b2f_lo(q2.x) + wt.w * b2f_lo(q3.x);
  float v1 = wt.x * b2f_hi(q0.x) + wt.y * b2f_hi(q1.x) +
             wt.z * b2f_hi(q2.x) + wt.w * b2f_hi(q3.x);
  float v2 = wt.x * b2f_lo(q0.y) + wt.y * b2f_lo(q1.y) +
             wt.z * b2f_lo(q2.y) + wt.w * b2f_lo(q3.y);
  float v3 = wt.x * b2f_hi(q0.y) + wt.y * b2f_hi(q1.y) +
             wt.z * b2f_hi(q2.y) + wt.w * b2f_hi(q3.y);
  uint2 r;
  r.x = (unsigned)f2b(v0) | ((unsigned)f2b(v1) << 16);
  r.y = (unsigned)f2b(v2) | ((unsigned)f2b(v3) << 16);
  *(uint2*)dst = r;
}

__global__ __launch_bounds__(256) void dcn_fused(
    const unsigned short* __restrict__ xt, const float* __restrict__ off,
    const float* __restrict__ mask, const __bf16* __restrict__ wbf,
    const float* __restrict__ bias, float* __restrict__ out) {
  extern __shared__ char smem_raw[];
  __bf16* As = (__bf16*)smem_raw;                        // 4 slots x 8192 el = 65536 B
  __bf16* Bs = As + 32768;                               // 4 slots x 1024 el =  8192 B
  float* swt = (float*)(Bs + 4096);                      // [9][32][4] f32 = 4608 B
  unsigned short* sidx = (unsigned short*)(swt + 1152);  // [9][32][4] u16 = 2304 B
  // total 80640 B -> 2 blocks/CU

  const int bid = blockIdx.x;
  const int id = ((bid & 7) << 6) | (bid >> 3);  // bijective, XCD-contig (512=8*64)
  const int b = id >> 7;
  const int nt = (id >> 1) & 63;  // h row
  const int nh = id & 1;          // half-row: w in [nh*32, nh*32+32)

  const int tid = threadIdx.x;
  const int lane = tid & 63;
  const int wave = tid >> 6;  // 4 waves, m-split 64 rows each
  const int lh = lane & 15, lg = lane >> 4;

  // ---- precompute per-(pos,k) tap weights & packed indices ----
  for (int e = tid; e < 288; e += 256) {
    const int k = e >> 5;    // 0..8
    const int pl = e & 31;   // 0..31
    const int w = nh * 32 + pl;
    float oy = off[(((size_t)b * 18 + 2 * k) * 64 + nt) * 64 + w];
    float ox = off[(((size_t)b * 18 + 2 * k + 1) * 64 + nt) * 64 + w];
    float m = mask[(((size_t)b * 9 + k) * 64 + nt) * 64 + w];
    float py = oy + (float)(nt - 1 + k / 3);
    float px = ox + (float)(w - 1 + k % 3);
    float y0f = floorf(py), x0f = floorf(px);
    float ly = py - y0f, lx = px - x0f;
    float hy = 1.f - ly, hx = 1.f - lx;
    int y0 = (int)y0f, x0 = (int)x0f;
    int y1 = y0 + 1, x1 = x0 + 1;
    bool vy0 = (y0 >= 0) && (y0 < 64);
    bool vy1 = (y1 >= 0) && (y1 < 64);
    bool vx0 = (x0 >= 0) && (x0 < 64);
    bool vx1 = (x1 >= 0) && (x1 < 64);
    int yc0 = min(max(y0, 0), 63), yc1 = min(max(y1, 0), 63);
    int xc0 = min(max(x0, 0), 63), xc1 = min(max(x1, 0), 63);
    unsigned short* sp = sidx + (k * 32 + pl) * 4;
    float* wp = swt + (k * 32 + pl) * 4;
    sp[0] = (unsigned short)(yc0 * 64 + xc0);
    sp[1] = (unsigned short)(yc0 * 64 + xc1);
    sp[2] = (unsigned short)(yc1 * 64 + xc0);
    sp[3] = (unsigned short)(yc1 * 64 + xc1);
    wp[0] = (vy0 && vx0) ? hy * hx * m : 0.f;
    wp[1] = (vy0 && vx1) ? hy * lx * m : 0.f;
    wp[2] = (vy1 && vx0) ? ly * hx * m : 0.f;
    wp[3] = (vy1 && vx1) ? ly * lx * m : 0.f;
  }

  // ---- A staging: tile = [256 rows][32 ch] = 16KB = 1024 chunks of 16B.
  // chunk c = j*256+tid: row=c>>2, col8=c&3, swizzled source col = col8^(row&3).
  const __bf16* aSrc[4];
  int aDst[4];
#pragma unroll
  for (int j = 0; j < 4; ++j) {
    const int c = j * 256 + tid;
    const int row = c >> 2;
    const int swz = (c & 3) ^ (row & 3);
    aSrc[j] = wbf + (size_t)row * 2304 + swz * 8;
    aDst[j] = c * 8;  // element offset within an As slot
  }
  // tile T covers K range (T>>3)*256 + (T&7)*32 + [0,32)
#define TBASE(T) (((T) >> 3) * 256 + ((T) & 7) * 32)

  // ---- B build: 8 threads/pos, 4 channels each (uint2 taps) ----
  const int pos = tid >> 3;  // 0..31
  const int ci = tid & 7;    // 4-ch group within the 32-ch tile
  const unsigned short* xtb = xt + (size_t)b * 1048576 + ci * 4;
  const int bsw = pos * 32 + (((ci >> 1) ^ (pos & 3)) << 3) + ((ci & 1) << 2);

  // ---- MFMA fragment offsets (col swizzle col' = lg ^ (lh&3)) ----
  const int csw = (lg ^ (lh & 3)) * 8;
  int aoff[4], boff[2];
#pragma unroll
  for (int fm = 0; fm < 4; ++fm) aoff[fm] = (wave * 64 + fm * 16 + lh) * 32 + csw;
#pragma unroll
  for (int fn = 0; fn < 2; ++fn) boff[fn] = (fn * 16 + lh) * 32 + csw;

#define STAGE_A(T, SLOT)                                                           \
  do {                                                                             \
    __bf16* AsD = As + (SLOT) * 8192;                                              \
    const int tb = TBASE(T);                                                       \
    G2L(aSrc[0] + tb, AsD + aDst[0]);                                              \
    G2L(aSrc[1] + tb, AsD + aDst[1]);                                              \
    G2L(aSrc[2] + tb, AsD + aDst[2]);                                              \
    G2L(aSrc[3] + tb, AsD + aDst[3]);                                              \
  } while (0)

#define LOADTAPS(Q0, Q1, Q2, Q3, T)                                                \
  do {                                                                             \
    uint2 su = *(const uint2*)(sidx + (((T) >> 3) * 32 + pos) * 4);                \
    const int co = ((T) & 7) * 32;                                                 \
    Q0 = *(const uint2*)(xtb + ((su.x & 0xFFFFu) << 8) + co);                      \
    Q1 = *(const uint2*)(xtb + ((su.x >> 16) << 8) + co);                          \
    Q2 = *(const uint2*)(xtb + ((su.y & 0xFFFFu) << 8) + co);                      \
    Q3 = *(const uint2*)(xtb + ((su.y >> 16) << 8) + co);                          \
  } while (0)

#define COMBINE(Q0, Q1, Q2, Q3, T, SLOT)                                           \
  do {                                                                             \
    float4 wt4 = *(const float4*)(swt + (((T) >> 3) * 32 + pos) * 4);              \
    combine4(Q0, Q1, Q2, Q3, wt4, Bs + (SLOT) * 1024 + bsw);                       \
  } while (0)

#define MFMA_TILE(ASLOT, BSLOT)                                                    \
  do {                                                                             \
    const __bf16* Ab = As + (ASLOT) * 8192;                                        \
    const __bf16* Bb = Bs + (BSLOT) * 1024;                                        \
    bf16x8 a[4], bv[2];                                                            \
    _Pragma("unroll") for (int fm = 0; fm < 4; ++fm)                               \
        a[fm] = *(const bf16x8*)(Ab + aoff[fm]);                                   \
    _Pragma("unroll") for (int fn = 0; fn < 2; ++fn)                               \
        bv[fn] = *(const bf16x8*)(Bb + boff[fn]);                                  \
    __builtin_amdgcn_s_setprio(1);                                                 \
    _Pragma("unroll") for (int fm = 0; fm < 4; ++fm)                               \
        _Pragma("unroll") for (int fn = 0; fn < 2; ++fn)                           \
            acc[fm][fn] = __builtin_amdgcn_mfma_f32_16x16x32_bf16(                 \
                a[fm], bv[fn], acc[fm][fn], 0, 0, 0);                              \
    __builtin_amdgcn_s_setprio(0);                                                 \
  } while (0)

#define WAIT_BAR(N)                                                                \
  do {                                                                             \
    asm volatile("s_waitcnt vmcnt(" #N ") lgkmcnt(0)" ::: "memory");               \
    __builtin_amdgcn_sched_barrier(0);                                             \
    __builtin_amdgcn_s_barrier();                                                  \
  } while (0)

  // superphase S: G2L{2S+2,2S+3}; taps{2S+4,2S+5}; combine{2S+2,2S+3} (taps from
  // S-1, implicit vmcnt(16)); MFMA{2S,2S+1}; WAIT_BAR(8).
#define SUPER(T0, FSLOT0, RSLOT0, L0a, L0b, L0c, L0d, L1a, L1b, L1c, L1d,          \
              C0a, C0b, C0c, C0d, C1a, C1b, C1c, C1d)                              \
  do {                                                                             \
    STAGE_A((T0) + 2, FSLOT0);                                                     \
    STAGE_A((T0) + 3, (FSLOT0) + 1);                                               \
    __builtin_amdgcn_sched_barrier(0);                                             \
    LOADTAPS(L0a, L0b, L0c, L0d, (T0) + 4);                                        \
    LOADTAPS(L1a, L1b, L1c, L1d, (T0) + 5);                                        \
    __builtin_amdgcn_sched_barrier(0);                                             \
    COMBINE(C0a, C0b, C0c, C0d, (T0) + 2, FSLOT0);                                 \
    COMBINE(C1a, C1b, C1c, C1d, (T0) + 3, (FSLOT0) + 1);                           \
    MFMA_TILE(RSLOT0, RSLOT0);                                                     \
    MFMA_TILE((RSLOT0) + 1, (RSLOT0) + 1);                                         \
    WAIT_BAR(8);                                                                   \
  } while (0)

  f32x4 acc[4][2] = {};
  uint2 e0, e1, e2, e3, e4, e5, e6, e7;  // TE: taps loaded in even superphases
  uint2 o0, o1, o2, o3, o4, o5, o6, o7;  // TO: taps loaded in odd superphases

  __syncthreads();  // swt/sidx ready

  // ---- prologue: combine tiles {0,1}; G2L{0,1}; taps{2,3} -> TO ----
  {
    LOADTAPS(e0, e1, e2, e3, 0);
    LOADTAPS(e4, e5, e6, e7, 1);
    COMBINE(e0, e1, e2, e3, 0, 0);
    COMBINE(e4, e5, e6, e7, 1, 1);
    STAGE_A(0, 0);
    STAGE_A(1, 1);
    __builtin_amdgcn_sched_barrier(0);
    LOADTAPS(o0, o1, o2, o3, 2);
    LOADTAPS(o4, o5, o6, o7, 3);
    WAIT_BAR(8);  // retire G2L{0,1}; TO taps{2,3} stay in flight
  }

  for (int p = 0; p < 17; ++p) {
    const int t4 = p * 4;
    // S = 2p (even): fill slots 2,3; read slots 0,1; loads TE; combines TO
    SUPER(t4, 2, 0, e0, e1, e2, e3, e4, e5, e6, e7,
          o0, o1, o2, o3, o4, o5, o6, o7);
    // S = 2p+1 (odd): fill slots 0,1; read slots 2,3; loads TO; combines TE
    SUPER(t4 + 2, 0, 2, o0, o1, o2, o3, o4, o5, o6, o7,
          e0, e1, e2, e3, e4, e5, e6, e7);
  }
  // ---- tail: S=34 (no tap prefetch), S=35 (MFMA only) ----
  {
    STAGE_A(70, 2);
    STAGE_A(71, 3);
    COMBINE(o0, o1, o2, o3, 70, 2);  // TO = taps{70,71} loaded at p=16 odd
    COMBINE(o4, o5, o6, o7, 71, 3);
    MFMA_TILE(0, 0);  // tile 68
    MFMA_TILE(1, 1);  // tile 69
    WAIT_BAR(0);
    MFMA_TILE(2, 2);  // tile 70
    MFMA_TILE(3, 3);  // tile 71
  }

  // ---- epilogue ----
  float* outb = out + (size_t)b * 1048576 + (size_t)(nt * 64 + nh * 32);
#pragma unroll
  for (int fm = 0; fm < 4; ++fm) {
#pragma unroll
    for (int i = 0; i < 4; ++i) {
      const int o = wave * 64 + fm * 16 + lg * 4 + i;
      const float bs = bias[o];
      float* orow = outb + (size_t)o * 4096 + lh;
#pragma unroll
      for (int fn = 0; fn < 2; ++fn) orow[fn * 16] = acc[fm][fn][i] + bs;
    }
  }
#undef SUPER
#undef MFMA_TILE
#undef COMBINE
#undef LOADTAPS
#undef STAGE_A
#undef WAIT_BAR
#undef TBASE
}

extern "C" void kernel_launch(void* const* d_in, const int* in_sizes, int n_in,
                              void* d_out, int out_size, void* d_ws, size_t ws_size,
                              hipStream_t stream) {
  const float* x = (const float*)d_in[0];
  const float* off = (const float*)d_in[1];
  const float* mask = (const float*)d_in[2];
  const float* wgt = (const float*)d_in[3];
  const float* bias = (const float*)d_in[4];
  float* out = (float*)d_out;

  unsigned short* wbf = (unsigned short*)d_ws;   // 256*2304 bf16 = 1.2 MB
  unsigned short* xtp = wbf + 589824ull;         // 4*64*64*256 bf16 = 8.4 MB

  const int smem_bytes = 65536 + 8192 + 4608 + 2304;  // 80640 -> 2 blocks/CU
  (void)hipFuncSetAttribute(reinterpret_cast<const void*>(&dcn_fused),
                            hipFuncAttributeMaxDynamicSharedMemorySize, smem_bytes);

  cast_weight<<<2304, 256, 0, stream>>>(wgt, wbf);
  transpose_x<<<1024, 256, 0, stream>>>(x, xtp);
  dcn_fused<<<512, 256, smem_bytes, stream>>>(xtp, off, mask, (const __bf16*)wbf,
                                              bias, out);
}